// Round 8
// baseline (19534.317 us; speedup 1.0000x reference)
//
#include <hip/hip_runtime.h>
#include <math.h>

#define TINYF 1.17549435e-38f
#define GMAX 16.0f        // hard upper bound on gumbel (15.9424) + slack
#define CANDCAP 262144

typedef __attribute__((ext_vector_type(8))) short short8;   // 8 bf16
typedef __attribute__((ext_vector_type(4))) float f32x4;

// ---------------- threefry2x32, key = (0, 42), partitionable xor-combine ----
__device__ __forceinline__ unsigned rotl32(unsigned x, int r) {
  return (x << r) | (x >> (32 - r));
}

__device__ __forceinline__ unsigned tf2x32_xor(unsigned x0, unsigned x1) {
  const unsigned k0 = 0u, k1 = 42u, k2 = 0x1BD11BF0u;  // 0x1BD11BDA ^ 0 ^ 42
  x0 += k0; x1 += k1;
#define TFR(r) { x0 += x1; x1 = rotl32(x1, r); x1 ^= x0; }
  TFR(13) TFR(15) TFR(26) TFR(6)
  x0 += k1; x1 += k2 + 1u;
  TFR(17) TFR(29) TFR(16) TFR(24)
  x0 += k2; x1 += k0 + 2u;
  TFR(13) TFR(15) TFR(26) TFR(6)
  x0 += k0; x1 += k1 + 3u;
  TFR(17) TFR(29) TFR(16) TFR(24)
  x0 += k1; x1 += k2 + 4u;
  TFR(13) TFR(15) TFR(26) TFR(6)
  x0 += k2; x1 += k0 + 5u;
#undef TFR
  return x0 ^ x1;
}

__device__ __forceinline__ float gumbel_from_bits(unsigned bits) {
  float f = __uint_as_float((bits >> 9) | 0x3f800000u) - 1.0f;
  float u = fmaxf(f, TINYF);
  return -logf(-logf(u));
}

// order-preserving float->uint (monotone)
__device__ __forceinline__ unsigned ordf(float v) {
  unsigned b = __float_as_uint(v);
  return (b & 0x80000000u) ? ~b : (b | 0x80000000u);
}

__device__ __forceinline__ unsigned short f2bf(float x) {  // RNE bf16
  unsigned u = __float_as_uint(x);
  return (unsigned short)((u + 0x7FFFu + ((u >> 16) & 1u)) >> 16);
}

// ---------------- init: zero rowslot/counter/maxA ----------------
__global__ void k_init(unsigned long long* rowslot, unsigned* cand_cnt,
                       float* maxA) {
  const int gid = blockIdx.x * 256 + threadIdx.x;
  if (gid < 4096) ((unsigned*)rowslot)[gid] = 0u;
  if (gid == 4096) *cand_cnt = 0u;
  if (gid == 4097) *maxA = 0.0f;
}

// ---------------- h = x @ W + b (f64 accumulate) ----------------
__global__ void k_hraw(const float* __restrict__ x, const float* __restrict__ W,
                       const float* __restrict__ b, float* __restrict__ hraw) {
  __shared__ float sx[256];
  const int i = blockIdx.x;
  const int d = threadIdx.x;  // 128 threads
  sx[d] = x[i * 256 + d];
  sx[d + 128] = x[i * 256 + 128 + d];
  __syncthreads();
  double acc = 0.0;
  for (int k = 0; k < 256; ++k)
    acc = fma((double)sx[k], (double)W[k * 128 + d], acc);
  hraw[i * 128 + d] = (float)acc + b[d];
}

// ---------------- BN stats per column (f64) ----------------
__global__ void k_bnstats(const float* __restrict__ hraw,
                          float* __restrict__ meanv, float* __restrict__ rsv) {
  __shared__ double red[256];
  const int d = blockIdx.x;   // 128 blocks
  const int t = threadIdx.x;  // 256 threads
  double s = 0.0;
  for (int i = t; i < 2048; i += 256) s += (double)hraw[i * 128 + d];
  red[t] = s;
  __syncthreads();
  for (int off = 128; off > 0; off >>= 1) {
    if (t < off) red[t] += red[t + off];
    __syncthreads();
  }
  const float m = (float)(red[0] * (1.0 / 2048.0));
  __syncthreads();
  double v = 0.0;
  for (int i = t; i < 2048; i += 256) {
    float dd = __fsub_rn(hraw[i * 128 + d], m);
    v += (double)dd * (double)dd;
  }
  red[t] = v;
  __syncthreads();
  for (int off = 128; off > 0; off >>= 1) {
    if (t < off) red[t] += red[t + off];
    __syncthreads();
  }
  if (t == 0) {
    float var = (float)(red[0] * (1.0 / 2048.0));
    float vpe = __fadd_rn(var, 1e-5f);
    meanv[d] = m;
    rsv[d] = (float)(1.0 / sqrt((double)vpe));
  }
}

// ---------------- apply BN + leaky relu ----------------
__global__ void k_apply(const float* __restrict__ hraw,
                        const float* __restrict__ meanv, const float* __restrict__ rsv,
                        const float* __restrict__ gamma, const float* __restrict__ beta,
                        float* __restrict__ hfin) {
  const int idx = blockIdx.x * 256 + threadIdx.x;
  const int d = idx & 127;
  float h = hraw[idx];
  float hn = __fadd_rn(__fmul_rn(__fmul_rn(__fsub_rn(h, meanv[d]), rsv[d]), gamma[d]), beta[d]);
  hfin[idx] = (hn >= 0.0f) ? hn : __fmul_rn(0.01f, hn);
}

// ---------------- h -> bf16 + row norms ----------------
__global__ void k_hbconv(const float* __restrict__ hfin,
                         unsigned short* __restrict__ hb,
                         float* __restrict__ hnorm) {
  const int r = blockIdx.x;      // 2048
  const int lane = threadIdx.x;  // 64
  float a = hfin[r * 128 + lane];
  float b = hfin[r * 128 + 64 + lane];
  hb[r * 128 + lane] = f2bf(a);
  hb[r * 128 + 64 + lane] = f2bf(b);
  float s = a * a + b * b;
  for (int off = 32; off > 0; off >>= 1) s += __shfl_down(s, off);
  if (lane == 0) hnorm[r] = sqrtf(s);
}

// ---------------- items -> bf16 + global max row norm ----------------
__global__ void k_ibconv(const float* __restrict__ items,
                         unsigned short* __restrict__ ib,
                         float* __restrict__ maxA) {
  const int r = blockIdx.x * 4 + (threadIdx.x >> 6);  // 12500 blocks x 4 rows
  const int lane = threadIdx.x & 63;
  float a = items[(size_t)r * 128 + lane];
  float b = items[(size_t)r * 128 + 64 + lane];
  ib[(size_t)r * 128 + lane] = f2bf(a);
  ib[(size_t)r * 128 + 64 + lane] = f2bf(b);
  float s = a * a + b * b;
  for (int off = 32; off > 0; off >>= 1) s += __shfl_down(s, off);
  if (lane == 0) atomicMax((int*)maxA, __float_as_int(sqrtf(s)));
}

// ---------------- V0 seed: per-row achieved max over j in [0,1024) ----------
__global__ void k_seed(const float* __restrict__ hfin,
                       const float* __restrict__ items,
                       float* __restrict__ V0) {
  __shared__ float red[4][256];
  const int t = threadIdx.x;
  const int rbase = blockIdx.x * 4;
  float best[4] = {-INFINITY, -INFINITY, -INFINITY, -INFINITY};
  for (int q = 0; q < 4; ++q) {
    const int j = t + 256 * q;
    float acc[4] = {0.0f, 0.0f, 0.0f, 0.0f};
    const float* ap = items + (size_t)j * 128;
    for (int km = 0; km < 8; ++km) {
#pragma unroll
      for (int e = 0; e < 4; ++e) {
        float4 a4 = *(const float4*)(ap + km * 16 + 4 * e);
        float4 h4[4];
#pragma unroll
        for (int p = 0; p < 4; ++p)
          h4[p] = *(const float4*)(hfin + (rbase + p) * 128 + km * 16 + 4 * e);
#pragma unroll
        for (int p = 0; p < 4; ++p) {
          acc[p] = fmaf(h4[p].x, a4.x, acc[p]);
          acc[p] = fmaf(h4[p].y, a4.y, acc[p]);
          acc[p] = fmaf(h4[p].z, a4.z, acc[p]);
          acc[p] = fmaf(h4[p].w, a4.w, acc[p]);
        }
      }
    }
#pragma unroll
    for (int p = 0; p < 4; ++p) {
      unsigned l = (unsigned)(rbase + p) * 50000u + (unsigned)j;
      float g = gumbel_from_bits(tf2x32_xor(0u, l));
      best[p] = fmaxf(best[p], acc[p] + g);
    }
  }
#pragma unroll
  for (int p = 0; p < 4; ++p) red[p][t] = best[p];
  __syncthreads();
  for (int off = 128; off > 0; off >>= 1) {
    if (t < off) {
#pragma unroll
      for (int p = 0; p < 4; ++p) red[p][t] = fmaxf(red[p][t], red[p][t + off]);
    }
    __syncthreads();
  }
  if (t < 4) V0[rbase + t] = red[t][0];
}

// ---------------- per-row candidate threshold ----------------
// vth = V0 - g_max - eps, eps >= |s_exact - s_bf16| (Cauchy-Schwarz:
// 2*2^-8 elementwise bf16 rel err + f32 accum slack)
__global__ void k_vth(const float* __restrict__ V0, const float* __restrict__ hnorm,
                      const float* __restrict__ maxA, float* __restrict__ vth) {
  const int i = blockIdx.x * 256 + threadIdx.x;
  if (i < 2048)
    vth[i] = V0[i] - GMAX - (0.0082f * hnorm[i] * maxA[0] + 0.05f);
}

// ---------------- MFMA screening pass ----------------
// grid 12800: c = bid&7 (chunk == XCD, bf16 chunk 1.6MB L2-resident),
// jt = (bid>>3)%25 (j-tile of 256 within chunk), rt = (bid>>3)/25 (32 rows).
// 4 waves x (2 M-tiles x 4 N-tiles) of mfma_f32_16x16x32_bf16.
// Lane holds C[reg] = approx score(row = r0+mt*16+q*4+reg, col = j0+(lane&15)).
__global__ __launch_bounds__(256) void k_mfma(
    const unsigned short* __restrict__ hb, const unsigned short* __restrict__ ib,
    const float* __restrict__ vth,
    const float* __restrict__ hfin, const float* __restrict__ items,
    unsigned* __restrict__ cand, unsigned* __restrict__ cand_cnt,
    unsigned long long* __restrict__ rowslot) {
  const int t = threadIdx.x;
  const int bid = blockIdx.x;
  const int c = bid & 7;
  const int tmp = bid >> 3;
  const int jt = tmp % 25;
  const int rt = tmp / 25;
  const int r0 = rt * 32;
  const int jlo = c * 6250;
  const int jhi = jlo + 6250;
  const int wid = t >> 6;
  const int lane = t & 63;
  const int m = lane & 15;
  const int q = lane >> 4;
  const int jw = jlo + jt * 256 + wid * 64;

  // A fragments: 2 M-tiles x 4 K-steps, A[m=lane&15][k=q*8+i]
  short8 afrag[2][4];
#pragma unroll
  for (int mt = 0; mt < 2; ++mt) {
    const unsigned short* hrow = hb + (r0 + mt * 16 + m) * 128 + q * 8;
#pragma unroll
    for (int ks = 0; ks < 4; ++ks)
      afrag[mt][ks] = *(const short8*)(hrow + ks * 32);
  }

#pragma unroll
  for (int nt = 0; nt < 4; ++nt) {
    const int jn = jw + nt * 16 + m;
    const int jcl = (jn < jhi) ? jn : (jhi - 1);
    const unsigned short* brow = ib + (size_t)jcl * 128 + q * 8;
    f32x4 C0 = {0.f, 0.f, 0.f, 0.f};
    f32x4 C1 = {0.f, 0.f, 0.f, 0.f};
#pragma unroll
    for (int ks = 0; ks < 4; ++ks) {
      short8 bfrag = *(const short8*)(brow + ks * 32);
      C0 = __builtin_amdgcn_mfma_f32_16x16x32_bf16(afrag[0][ks], bfrag, C0, 0, 0, 0);
      C1 = __builtin_amdgcn_mfma_f32_16x16x32_bf16(afrag[1][ks], bfrag, C1, 0, 0, 0);
    }
    if (jn < jhi) {
#pragma unroll
      for (int reg = 0; reg < 4; ++reg) {
#pragma unroll
        for (int mt = 0; mt < 2; ++mt) {
          const int grow = r0 + mt * 16 + q * 4 + reg;
          const float s = (mt == 0) ? C0[reg] : C1[reg];
          if (s >= vth[grow]) {
            unsigned slot = atomicAdd(cand_cnt, 1u);
            if (slot < CANDCAP) {
              cand[slot] = ((unsigned)grow << 16) | (unsigned)jn;
            } else {  // overflow fallback: exact inline (never expected)
              const float* hp = hfin + grow * 128;
              const float* ap = items + (size_t)jn * 128;
              float acc = 0.f;
              for (int k = 0; k < 128; ++k) acc = fmaf(hp[k], ap[k], acc);
              unsigned l = (unsigned)grow * 50000u + (unsigned)jn;
              float v = acc + gumbel_from_bits(tf2x32_xor(0u, l));
              unsigned long long pk =
                  ((unsigned long long)ordf(v) << 32) | (0xFFFFFFFFu - (unsigned)jn);
              atomicMax(&rowslot[grow], pk);
            }
          }
        }
      }
    }
  }
}

// ---------------- exact rescore of candidates ----------------
__global__ void k_rescore(const unsigned* __restrict__ cand,
                          const unsigned* __restrict__ cand_cnt,
                          const float* __restrict__ hfin,
                          const float* __restrict__ items,
                          unsigned long long* __restrict__ rowslot) {
  unsigned n = *cand_cnt;
  if (n > CANDCAP) n = CANDCAP;
  for (unsigned i = blockIdx.x * 256 + threadIdx.x; i < n; i += gridDim.x * 256) {
    const unsigned key = cand[i];
    const unsigned grow = key >> 16;
    const unsigned j = key & 0xFFFFu;
    const float* hp = hfin + grow * 128;
    const float* ap = items + (size_t)j * 128;
    float acc = 0.f;
    for (int k = 0; k < 128; k += 4) {  // strictly sequential k (matches ref)
      float4 h4 = *(const float4*)(hp + k);
      float4 a4 = *(const float4*)(ap + k);
      acc = fmaf(h4.x, a4.x, acc);
      acc = fmaf(h4.y, a4.y, acc);
      acc = fmaf(h4.z, a4.z, acc);
      acc = fmaf(h4.w, a4.w, acc);
    }
    unsigned l = grow * 50000u + j;
    float v = acc + gumbel_from_bits(tf2x32_xor(0u, l));
    unsigned long long pk = ((unsigned long long)ordf(v) << 32) | (0xFFFFFFFFu - j);
    atomicMax(&rowslot[grow], pk);
  }
}

// ---------------- winner + cosine sim (one wave per row) ----------------
__global__ void k_final(const unsigned long long* __restrict__ rowslot,
                        const int* __restrict__ uid, const float* __restrict__ items,
                        float* __restrict__ dout, float* __restrict__ simv) {
  const int r = blockIdx.x;
  const int lane = threadIdx.x;  // 64
  const int bi = (int)(0xFFFFFFFFu - (unsigned)(rowslot[r] & 0xFFFFFFFFull));
  if (lane == 0) dout[r] = (float)bi;

  const int orig = uid[r * 2 + 1];
  float o1 = items[(size_t)orig * 128 + lane];
  float o2 = items[(size_t)orig * 128 + 64 + lane];
  float p1 = items[(size_t)bi * 128 + lane];
  float p2 = items[(size_t)bi * 128 + 64 + lane];
  float d = o1 * p1 + o2 * p2;
  float s1 = o1 * o1 + o2 * o2;
  float s2 = p1 * p1 + p2 * p2;
  for (int off = 32; off > 0; off >>= 1) {
    d += __shfl_down(d, off);
    s1 += __shfl_down(s1, off);
    s2 += __shfl_down(s2, off);
  }
  if (lane == 0) {
    float n1 = fmaxf(sqrtf(s1), 1e-6f);
    float n2 = fmaxf(sqrtf(s2), 1e-6f);
    float sim = d / (n1 * n2);
    simv[r] = (sim + 1.0f) * 0.5f;
  }
}

// ---------------- final scalar reductions ----------------
__global__ void k_reduce(const float* __restrict__ simv, float* __restrict__ dout) {
  __shared__ double rl[256];
  __shared__ double rs[256];
  const int t = threadIdx.x;
  double L = 0.0, S = 0.0;
  for (int i = t; i < 2048; i += 256) {
    double s = (double)simv[i];
    double dd = s - 0.5;
    L += dd * dd;
    S += s;
  }
  rl[t] = L; rs[t] = S;
  __syncthreads();
  for (int off = 128; off > 0; off >>= 1) {
    if (t < off) { rl[t] += rl[t + off]; rs[t] += rs[t + off]; }
    __syncthreads();
  }
  if (t == 0) {
    dout[2048] = (float)(rl[0] * (1.0 / 2048.0));
    dout[2049] = (float)(rs[0] * (1.0 / 2048.0));
  }
}

extern "C" void kernel_launch(void* const* d_in, const int* in_sizes, int n_in,
                              void* d_out, int out_size, void* d_ws, size_t ws_size,
                              hipStream_t stream) {
  const int* uid = (const int*)d_in[0];       // (2048,2) int32
  const float* xfeat = (const float*)d_in[1]; // (2048,256)
  const float* items = (const float*)d_in[2]; // (50000,128)
  const float* W = (const float*)d_in[3];     // (256,128)
  const float* bias = (const float*)d_in[4];  // (128,)
  const float* gamma = (const float*)d_in[5]; // (128,)
  const float* beta = (const float*)d_in[6];  // (128,)

  float* ws = (float*)d_ws;
  float* hraw = ws;                                   // 262144
  float* hfin = ws + 262144;                          // 262144
  float* meanv = ws + 524288;                         // 128
  float* rsv = ws + 524416;                           // 128
  float* V0 = ws + 524544;                            // 2048
  float* hnorm = ws + 526592;                         // 2048
  float* vth = ws + 528640;                           // 2048
  float* simv = ws + 530688;                          // 2048
  float* maxA = ws + 532736;                          // 1
  unsigned* cand_cnt = (unsigned*)(ws + 532737);      // 1
  unsigned long long* rowslot =
      (unsigned long long*)(ws + 532744);             // 2048 u64
  unsigned* cand = (unsigned*)(ws + 536840);          // 262144 u32
  unsigned short* hb = (unsigned short*)(ws + 798984);   // 262144 bf16
  unsigned short* ib = (unsigned short*)(ws + 930056);   // 6.4M bf16
  float* dout = (float*)d_out;                        // 2050 floats

  hipLaunchKernelGGL(k_init, dim3(17), dim3(256), 0, stream, rowslot, cand_cnt, maxA);
  hipLaunchKernelGGL(k_hraw, dim3(2048), dim3(128), 0, stream, xfeat, W, bias, hraw);
  hipLaunchKernelGGL(k_bnstats, dim3(128), dim3(256), 0, stream, hraw, meanv, rsv);
  hipLaunchKernelGGL(k_apply, dim3(1024), dim3(256), 0, stream, hraw, meanv, rsv, gamma, beta, hfin);
  hipLaunchKernelGGL(k_hbconv, dim3(2048), dim3(64), 0, stream, hfin, hb, hnorm);
  hipLaunchKernelGGL(k_ibconv, dim3(12500), dim3(256), 0, stream, items, ib, maxA);
  hipLaunchKernelGGL(k_seed, dim3(512), dim3(256), 0, stream, hfin, items, V0);
  hipLaunchKernelGGL(k_vth, dim3(8), dim3(256), 0, stream, V0, hnorm, maxA, vth);
  hipLaunchKernelGGL(k_mfma, dim3(12800), dim3(256), 0, stream,
                     hb, ib, vth, hfin, items, cand, cand_cnt, rowslot);
  hipLaunchKernelGGL(k_rescore, dim3(64), dim3(256), 0, stream,
                     cand, cand_cnt, hfin, items, rowslot);
  hipLaunchKernelGGL(k_final, dim3(2048), dim3(64), 0, stream, rowslot, uid, items, dout, simv);
  hipLaunchKernelGGL(k_reduce, dim3(1), dim3(256), 0, stream, simv, dout);
}

// Round 9
// 2371.074 us; speedup vs baseline: 8.2386x; 8.2386x over previous
//
#include <hip/hip_runtime.h>
#include <math.h>

#define TINYF 1.17549435e-38f
#define GMAX 16.0f        // hard upper bound on gumbel (15.9424) + slack
#define CANDCAP 3000000
#define LQCAP 4096

typedef __attribute__((ext_vector_type(8))) short short8;   // 8 bf16
typedef __attribute__((ext_vector_type(4))) float f32x4;

// ---------------- threefry2x32, key = (0, 42), partitionable xor-combine ----
__device__ __forceinline__ unsigned rotl32(unsigned x, int r) {
  return (x << r) | (x >> (32 - r));
}

__device__ __forceinline__ unsigned tf2x32_xor(unsigned x0, unsigned x1) {
  const unsigned k0 = 0u, k1 = 42u, k2 = 0x1BD11BF0u;  // 0x1BD11BDA ^ 0 ^ 42
  x0 += k0; x1 += k1;
#define TFR(r) { x0 += x1; x1 = rotl32(x1, r); x1 ^= x0; }
  TFR(13) TFR(15) TFR(26) TFR(6)
  x0 += k1; x1 += k2 + 1u;
  TFR(17) TFR(29) TFR(16) TFR(24)
  x0 += k2; x1 += k0 + 2u;
  TFR(13) TFR(15) TFR(26) TFR(6)
  x0 += k0; x1 += k1 + 3u;
  TFR(17) TFR(29) TFR(16) TFR(24)
  x0 += k1; x1 += k2 + 4u;
  TFR(13) TFR(15) TFR(26) TFR(6)
  x0 += k2; x1 += k0 + 5u;
#undef TFR
  return x0 ^ x1;
}

__device__ __forceinline__ float gumbel_from_bits(unsigned bits) {
  float f = __uint_as_float((bits >> 9) | 0x3f800000u) - 1.0f;
  float u = fmaxf(f, TINYF);
  return -logf(-logf(u));
}

// order-preserving float->uint (monotone)
__device__ __forceinline__ unsigned ordf(float v) {
  unsigned b = __float_as_uint(v);
  return (b & 0x80000000u) ? ~b : (b | 0x80000000u);
}

__device__ __forceinline__ unsigned short f2bf(float x) {  // RNE bf16
  unsigned u = __float_as_uint(x);
  return (unsigned short)((u + 0x7FFFu + ((u >> 16) & 1u)) >> 16);
}

// ---------------- init: zero state + build gumbel mantissa-cut table --------
// Bcut[k]: if (bits>>9) < Bcut[k] then g_f32(bits) < k, guaranteed (binary
// search against the SAME f32 logf path the rescore uses, -2 safety steps).
__global__ void k_init(unsigned long long* rowslot, unsigned* cand_cnt,
                       float* maxA, unsigned* Bcut) {
  const int gid = blockIdx.x * 256 + threadIdx.x;
  if (gid < 4096) ((unsigned*)rowslot)[gid] = 0u;
  if (gid == 4096) *cand_cnt = 0u;
  if (gid == 4097) *maxA = 0.0f;
  if (blockIdx.x == 16 && threadIdx.x < 16) {
    const int k = threadIdx.x;
    if (k == 0) { Bcut[0] = 0u; return; }
    unsigned lo = 1u, hi = 1u << 23;  // first B with g(B) >= k
    while (lo < hi) {
      unsigned mid = (lo + hi) >> 1;
      float u = (float)mid * 0x1p-23f;
      float g = -logf(-logf(u));
      if (g >= (float)k) hi = mid; else lo = mid + 1;
    }
    Bcut[k] = (lo >= 2u) ? (lo - 2u) : 0u;
  }
}

// ---------------- h = x @ W + b (f64 accumulate) ----------------
__global__ void k_hraw(const float* __restrict__ x, const float* __restrict__ W,
                       const float* __restrict__ b, float* __restrict__ hraw) {
  __shared__ float sx[256];
  const int i = blockIdx.x;
  const int d = threadIdx.x;  // 128 threads
  sx[d] = x[i * 256 + d];
  sx[d + 128] = x[i * 256 + 128 + d];
  __syncthreads();
  double acc = 0.0;
  for (int k = 0; k < 256; ++k)
    acc = fma((double)sx[k], (double)W[k * 128 + d], acc);
  hraw[i * 128 + d] = (float)acc + b[d];
}

// ---------------- BN stats per column (f64) ----------------
__global__ void k_bnstats(const float* __restrict__ hraw,
                          float* __restrict__ meanv, float* __restrict__ rsv) {
  __shared__ double red[256];
  const int d = blockIdx.x;   // 128 blocks
  const int t = threadIdx.x;  // 256 threads
  double s = 0.0;
  for (int i = t; i < 2048; i += 256) s += (double)hraw[i * 128 + d];
  red[t] = s;
  __syncthreads();
  for (int off = 128; off > 0; off >>= 1) {
    if (t < off) red[t] += red[t + off];
    __syncthreads();
  }
  const float m = (float)(red[0] * (1.0 / 2048.0));
  __syncthreads();
  double v = 0.0;
  for (int i = t; i < 2048; i += 256) {
    float dd = __fsub_rn(hraw[i * 128 + d], m);
    v += (double)dd * (double)dd;
  }
  red[t] = v;
  __syncthreads();
  for (int off = 128; off > 0; off >>= 1) {
    if (t < off) red[t] += red[t + off];
    __syncthreads();
  }
  if (t == 0) {
    float var = (float)(red[0] * (1.0 / 2048.0));
    float vpe = __fadd_rn(var, 1e-5f);
    meanv[d] = m;
    rsv[d] = (float)(1.0 / sqrt((double)vpe));
  }
}

// ---------------- apply BN + leaky relu ----------------
__global__ void k_apply(const float* __restrict__ hraw,
                        const float* __restrict__ meanv, const float* __restrict__ rsv,
                        const float* __restrict__ gamma, const float* __restrict__ beta,
                        float* __restrict__ hfin) {
  const int idx = blockIdx.x * 256 + threadIdx.x;
  const int d = idx & 127;
  float h = hraw[idx];
  float hn = __fadd_rn(__fmul_rn(__fmul_rn(__fsub_rn(h, meanv[d]), rsv[d]), gamma[d]), beta[d]);
  hfin[idx] = (hn >= 0.0f) ? hn : __fmul_rn(0.01f, hn);
}

// ---------------- h -> bf16 + row norms ----------------
__global__ void k_hbconv(const float* __restrict__ hfin,
                         unsigned short* __restrict__ hb,
                         float* __restrict__ hnorm) {
  const int r = blockIdx.x;      // 2048
  const int lane = threadIdx.x;  // 64
  float a = hfin[r * 128 + lane];
  float b = hfin[r * 128 + 64 + lane];
  hb[r * 128 + lane] = f2bf(a);
  hb[r * 128 + 64 + lane] = f2bf(b);
  float s = a * a + b * b;
  for (int off = 32; off > 0; off >>= 1) s += __shfl_down(s, off);
  if (lane == 0) hnorm[r] = sqrtf(s) * 1.000001f;
}

// ---------------- items -> bf16 + global max row norm ----------------
__global__ void k_ibconv(const float* __restrict__ items,
                         unsigned short* __restrict__ ib,
                         float* __restrict__ maxA) {
  const int r = blockIdx.x * 4 + (threadIdx.x >> 6);  // 12500 blocks x 4 rows
  const int lane = threadIdx.x & 63;
  float a = items[(size_t)r * 128 + lane];
  float b = items[(size_t)r * 128 + 64 + lane];
  ib[(size_t)r * 128 + lane] = f2bf(a);
  ib[(size_t)r * 128 + 64 + lane] = f2bf(b);
  float s = a * a + b * b;
  for (int off = 32; off > 0; off >>= 1) s += __shfl_down(s, off);
  if (lane == 0) atomicMax((int*)maxA, __float_as_int(sqrtf(s) * 1.000001f));
}

// ---------------- V0 seed over j in [0,1024) + per-row threshold -----------
// vth = V0 - GMAX - eps, eps >= |s_exact - s_bf16| (Cauchy-Schwarz bf16 bound)
__global__ void k_seedvth(const float* __restrict__ hfin,
                          const float* __restrict__ items,
                          const float* __restrict__ hnorm,
                          const float* __restrict__ maxA,
                          float* __restrict__ vth) {
  __shared__ float red[4][256];
  const int t = threadIdx.x;
  const int rbase = blockIdx.x * 4;
  float best[4] = {-INFINITY, -INFINITY, -INFINITY, -INFINITY};
  for (int q = 0; q < 4; ++q) {
    const int j = t + 256 * q;
    float acc[4] = {0.0f, 0.0f, 0.0f, 0.0f};
    const float* ap = items + (size_t)j * 128;
    for (int km = 0; km < 8; ++km) {
#pragma unroll
      for (int e = 0; e < 4; ++e) {
        float4 a4 = *(const float4*)(ap + km * 16 + 4 * e);
        float4 h4[4];
#pragma unroll
        for (int p = 0; p < 4; ++p)
          h4[p] = *(const float4*)(hfin + (rbase + p) * 128 + km * 16 + 4 * e);
#pragma unroll
        for (int p = 0; p < 4; ++p) {
          acc[p] = fmaf(h4[p].x, a4.x, acc[p]);
          acc[p] = fmaf(h4[p].y, a4.y, acc[p]);
          acc[p] = fmaf(h4[p].z, a4.z, acc[p]);
          acc[p] = fmaf(h4[p].w, a4.w, acc[p]);
        }
      }
    }
#pragma unroll
    for (int p = 0; p < 4; ++p) {
      unsigned l = (unsigned)(rbase + p) * 50000u + (unsigned)j;
      float g = gumbel_from_bits(tf2x32_xor(0u, l));
      best[p] = fmaxf(best[p], acc[p] + g);
    }
  }
#pragma unroll
  for (int p = 0; p < 4; ++p) red[p][t] = best[p];
  __syncthreads();
  for (int off = 128; off > 0; off >>= 1) {
    if (t < off) {
#pragma unroll
      for (int p = 0; p < 4; ++p) red[p][t] = fmaxf(red[p][t], red[p][t + off]);
    }
    __syncthreads();
  }
  if (t < 4) {
    const int r = rbase + t;
    vth[r] = red[t][0] - GMAX - (0.0082f * hnorm[r] * maxA[0] + 0.05f);
  }
}

// ---------------- MFMA screening + 2-stage prune ----------------
// grid 12800: c = bid&7 (chunk == XCD, bf16 chunk 1.6MB L2-resident),
// jt = (bid>>3)%25, rt = (bid>>3)/25 (32 rows). 4 waves x 2 M x 4 N tiles of
// mfma_f32_16x16x32_bf16. Stage 1 (s >= vth) -> LDS queue (~10% pass).
// Stage 2 (dense): threefry BITS only + mantissa-table test kills everything
// whose gumbel provably can't reach V0 -> global cand (~<1% of stage 1).
__global__ __launch_bounds__(256) void k_mfma(
    const unsigned short* __restrict__ hb, const unsigned short* __restrict__ ib,
    const float* __restrict__ vth, const unsigned* __restrict__ Bcut,
    const float* __restrict__ hfin, const float* __restrict__ items,
    unsigned* __restrict__ cand, unsigned* __restrict__ cand_cnt,
    unsigned long long* __restrict__ rowslot) {
  __shared__ unsigned q_key[LQCAP];
  __shared__ float q_val[LQCAP];
  __shared__ unsigned sBcut[16];
  __shared__ unsigned q_cnt;

  const int t = threadIdx.x;
  const int bid = blockIdx.x;
  const int c = bid & 7;
  const int tmp = bid >> 3;
  const int jt = tmp % 25;
  const int rt = tmp / 25;
  const int r0 = rt * 32;
  const int jlo = c * 6250;
  const int jhi = jlo + 6250;
  const int wid = t >> 6;
  const int lane = t & 63;
  const int m = lane & 15;
  const int q = lane >> 4;
  const int jw = jlo + jt * 256 + wid * 64;

  if (t < 16) sBcut[t] = Bcut[t];
  if (t == 0) q_cnt = 0;
  __syncthreads();

  // A fragments: A[m=lane&15][k=q*8+i], 2 M-tiles x 4 K-steps
  short8 afrag[2][4];
  float vthr[2][4];
#pragma unroll
  for (int mt = 0; mt < 2; ++mt) {
    const unsigned short* hrow = hb + (r0 + mt * 16 + m) * 128 + q * 8;
#pragma unroll
    for (int ks = 0; ks < 4; ++ks) afrag[mt][ks] = *(const short8*)(hrow + ks * 32);
#pragma unroll
    for (int reg = 0; reg < 4; ++reg) vthr[mt][reg] = vth[r0 + mt * 16 + q * 4 + reg];
  }

#pragma unroll
  for (int nt = 0; nt < 4; ++nt) {
    const int jn = jw + nt * 16 + m;
    const int jcl = (jn < jhi) ? jn : (jhi - 1);
    const unsigned short* brow = ib + (size_t)jcl * 128 + q * 8;
    f32x4 C0 = {0.f, 0.f, 0.f, 0.f};
    f32x4 C1 = {0.f, 0.f, 0.f, 0.f};
#pragma unroll
    for (int ks = 0; ks < 4; ++ks) {
      short8 bfrag = *(const short8*)(brow + ks * 32);
      C0 = __builtin_amdgcn_mfma_f32_16x16x32_bf16(afrag[0][ks], bfrag, C0, 0, 0, 0);
      C1 = __builtin_amdgcn_mfma_f32_16x16x32_bf16(afrag[1][ks], bfrag, C1, 0, 0, 0);
    }
    if (jn < jhi) {
#pragma unroll
      for (int reg = 0; reg < 4; ++reg) {
#pragma unroll
        for (int mt = 0; mt < 2; ++mt) {
          const float s = (mt == 0) ? C0[reg] : C1[reg];
          if (s >= vthr[mt][reg]) {
            const unsigned p = (unsigned)(mt * 16 + q * 4 + reg);
            unsigned slot = atomicAdd(&q_cnt, 1u);
            if (slot < LQCAP) {
              q_key[slot] = (p << 16) | (unsigned)jn;
              q_val[slot] = s;
            } else {  // LDS overflow: push raw to global (rescore is exact)
              unsigned g = atomicAdd(cand_cnt, 1u);
              if (g < CANDCAP)
                cand[g] = ((unsigned)(r0 + p) << 16) | (unsigned)jn;
            }
          }
        }
      }
    }
  }

  __syncthreads();
  // stage 2: dense, bits-only gumbel bound
  const unsigned n = (q_cnt < LQCAP) ? q_cnt : LQCAP;
  for (unsigned i = t; i < n; i += 256) {
    const unsigned key = q_key[i];
    const unsigned p = key >> 16;
    const unsigned j = key & 0xFFFFu;
    const float s = q_val[i];
    const unsigned grow = (unsigned)r0 + p;
    const float x = vth[grow] + GMAX - s;  // = V0 - eps - s
    const int k = (int)floorf(x - 0.01f);
    bool push;
    unsigned bits = 0u;
    if (k >= 16) {
      push = false;  // g <= 15.9424 < x
    } else if (k >= 1) {
      bits = tf2x32_xor(0u, grow * 50000u + j);
      push = ((bits >> 9) >= sBcut[k]);  // B < Bcut[k] => g < k <= x => skip
    } else {
      push = true;
    }
    if (push) {
      unsigned g = atomicAdd(cand_cnt, 1u);
      if (g < CANDCAP) {
        cand[g] = (grow << 16) | j;
      } else {  // global overflow: exact inline
        const float* hp = hfin + grow * 128;
        const float* ap = items + (size_t)j * 128;
        float acc = 0.f;
        for (int kk = 0; kk < 128; kk += 4) {
          float4 h4 = *(const float4*)(hp + kk);
          float4 a4 = *(const float4*)(ap + kk);
          acc = fmaf(h4.x, a4.x, acc);
          acc = fmaf(h4.y, a4.y, acc);
          acc = fmaf(h4.z, a4.z, acc);
          acc = fmaf(h4.w, a4.w, acc);
        }
        float v = acc + gumbel_from_bits(tf2x32_xor(0u, grow * 50000u + j));
        unsigned long long pk =
            ((unsigned long long)ordf(v) << 32) | (0xFFFFFFFFu - j);
        atomicMax(&rowslot[grow], pk);
      }
    }
  }
}

// ---------------- exact rescore of candidates ----------------
__global__ void k_rescore(const unsigned* __restrict__ cand,
                          const unsigned* __restrict__ cand_cnt,
                          const float* __restrict__ hfin,
                          const float* __restrict__ items,
                          unsigned long long* __restrict__ rowslot) {
  unsigned n = *cand_cnt;
  if (n > CANDCAP) n = CANDCAP;
  for (unsigned i = blockIdx.x * 256 + threadIdx.x; i < n; i += gridDim.x * 256) {
    const unsigned key = cand[i];
    const unsigned grow = key >> 16;
    const unsigned j = key & 0xFFFFu;
    const float* hp = hfin + grow * 128;
    const float* ap = items + (size_t)j * 128;
    float acc = 0.f;
    for (int k = 0; k < 128; k += 4) {  // strictly sequential k (matches ref)
      float4 h4 = *(const float4*)(hp + k);
      float4 a4 = *(const float4*)(ap + k);
      acc = fmaf(h4.x, a4.x, acc);
      acc = fmaf(h4.y, a4.y, acc);
      acc = fmaf(h4.z, a4.z, acc);
      acc = fmaf(h4.w, a4.w, acc);
    }
    unsigned l = grow * 50000u + j;
    float v = acc + gumbel_from_bits(tf2x32_xor(0u, l));
    unsigned long long pk = ((unsigned long long)ordf(v) << 32) | (0xFFFFFFFFu - j);
    atomicMax(&rowslot[grow], pk);
  }
}

// ---------------- winner + cosine sim (one wave per row) ----------------
__global__ void k_final(const unsigned long long* __restrict__ rowslot,
                        const int* __restrict__ uid, const float* __restrict__ items,
                        float* __restrict__ dout, float* __restrict__ simv) {
  const int r = blockIdx.x;
  const int lane = threadIdx.x;  // 64
  const int bi = (int)(0xFFFFFFFFu - (unsigned)(rowslot[r] & 0xFFFFFFFFull));
  if (lane == 0) dout[r] = (float)bi;

  const int orig = uid[r * 2 + 1];
  float o1 = items[(size_t)orig * 128 + lane];
  float o2 = items[(size_t)orig * 128 + 64 + lane];
  float p1 = items[(size_t)bi * 128 + lane];
  float p2 = items[(size_t)bi * 128 + 64 + lane];
  float d = o1 * p1 + o2 * p2;
  float s1 = o1 * o1 + o2 * o2;
  float s2 = p1 * p1 + p2 * p2;
  for (int off = 32; off > 0; off >>= 1) {
    d += __shfl_down(d, off);
    s1 += __shfl_down(s1, off);
    s2 += __shfl_down(s2, off);
  }
  if (lane == 0) {
    float n1 = fmaxf(sqrtf(s1), 1e-6f);
    float n2 = fmaxf(sqrtf(s2), 1e-6f);
    float sim = d / (n1 * n2);
    simv[r] = (sim + 1.0f) * 0.5f;
  }
}

// ---------------- final scalar reductions ----------------
__global__ void k_reduce(const float* __restrict__ simv, float* __restrict__ dout) {
  __shared__ double rl[256];
  __shared__ double rs[256];
  const int t = threadIdx.x;
  double L = 0.0, S = 0.0;
  for (int i = t; i < 2048; i += 256) {
    double s = (double)simv[i];
    double dd = s - 0.5;
    L += dd * dd;
    S += s;
  }
  rl[t] = L; rs[t] = S;
  __syncthreads();
  for (int off = 128; off > 0; off >>= 1) {
    if (t < off) { rl[t] += rl[t + off]; rs[t] += rs[t + off]; }
    __syncthreads();
  }
  if (t == 0) {
    dout[2048] = (float)(rl[0] * (1.0 / 2048.0));
    dout[2049] = (float)(rs[0] * (1.0 / 2048.0));
  }
}

extern "C" void kernel_launch(void* const* d_in, const int* in_sizes, int n_in,
                              void* d_out, int out_size, void* d_ws, size_t ws_size,
                              hipStream_t stream) {
  const int* uid = (const int*)d_in[0];       // (2048,2) int32
  const float* xfeat = (const float*)d_in[1]; // (2048,256)
  const float* items = (const float*)d_in[2]; // (50000,128)
  const float* W = (const float*)d_in[3];     // (256,128)
  const float* bias = (const float*)d_in[4];  // (128,)
  const float* gamma = (const float*)d_in[5]; // (128,)
  const float* beta = (const float*)d_in[6];  // (128,)

  float* ws = (float*)d_ws;
  float* hraw = ws;                                   // 262144
  float* hfin = ws + 262144;                          // 262144
  float* meanv = ws + 524288;                         // 128
  float* rsv = ws + 524416;                           // 128
  float* hnorm = ws + 524544;                         // 2048
  float* vth = ws + 526592;                           // 2048
  float* simv = ws + 528640;                          // 2048
  float* maxA = ws + 530688;                          // 1
  unsigned* cand_cnt = (unsigned*)(ws + 530689);      // 1
  unsigned long long* rowslot =
      (unsigned long long*)(ws + 530696);             // 2048 u64 (8B-aligned)
  unsigned* Bcut = (unsigned*)(ws + 534792);          // 16 u32
  unsigned* cand = (unsigned*)(ws + 534808);          // 3,000,000 u32
  unsigned short* hb = (unsigned short*)(ws + 3534808);  // 262144 bf16
  unsigned short* ib = (unsigned short*)(ws + 3665880);  // 6.4M bf16
  float* dout = (float*)d_out;                        // 2050 floats

  hipLaunchKernelGGL(k_init, dim3(17), dim3(256), 0, stream, rowslot, cand_cnt, maxA, Bcut);
  hipLaunchKernelGGL(k_hraw, dim3(2048), dim3(128), 0, stream, xfeat, W, bias, hraw);
  hipLaunchKernelGGL(k_bnstats, dim3(128), dim3(256), 0, stream, hraw, meanv, rsv);
  hipLaunchKernelGGL(k_apply, dim3(1024), dim3(256), 0, stream, hraw, meanv, rsv, gamma, beta, hfin);
  hipLaunchKernelGGL(k_hbconv, dim3(2048), dim3(64), 0, stream, hfin, hb, hnorm);
  hipLaunchKernelGGL(k_ibconv, dim3(12500), dim3(256), 0, stream, items, ib, maxA);
  hipLaunchKernelGGL(k_seedvth, dim3(512), dim3(256), 0, stream, hfin, items, hnorm, maxA, vth);
  hipLaunchKernelGGL(k_mfma, dim3(12800), dim3(256), 0, stream,
                     hb, ib, vth, Bcut, hfin, items, cand, cand_cnt, rowslot);
  hipLaunchKernelGGL(k_rescore, dim3(256), dim3(256), 0, stream,
                     cand, cand_cnt, hfin, items, rowslot);
  hipLaunchKernelGGL(k_final, dim3(2048), dim3(64), 0, stream, rowslot, uid, items, dout, simv);
  hipLaunchKernelGGL(k_reduce, dim3(1), dim3(256), 0, stream, simv, dout);
}

// Round 10
// 1178.393 us; speedup vs baseline: 16.5771x; 2.0121x over previous
//
#include <hip/hip_runtime.h>
#include <math.h>

#define TINYF 1.17549435e-38f
#define GMAX 16.0f        // hard upper bound on gumbel (15.9424) + slack
#define LQCAP 4096

typedef __attribute__((ext_vector_type(8))) short short8;   // 8 bf16
typedef __attribute__((ext_vector_type(4))) float f32x4;

// ---------------- threefry2x32, key = (0, 42), partitionable xor-combine ----
__device__ __forceinline__ unsigned rotl32(unsigned x, int r) {
  return (x << r) | (x >> (32 - r));
}

__device__ __forceinline__ unsigned tf2x32_xor(unsigned x0, unsigned x1) {
  const unsigned k0 = 0u, k1 = 42u, k2 = 0x1BD11BF0u;  // 0x1BD11BDA ^ 0 ^ 42
  x0 += k0; x1 += k1;
#define TFR(r) { x0 += x1; x1 = rotl32(x1, r); x1 ^= x0; }
  TFR(13) TFR(15) TFR(26) TFR(6)
  x0 += k1; x1 += k2 + 1u;
  TFR(17) TFR(29) TFR(16) TFR(24)
  x0 += k2; x1 += k0 + 2u;
  TFR(13) TFR(15) TFR(26) TFR(6)
  x0 += k0; x1 += k1 + 3u;
  TFR(17) TFR(29) TFR(16) TFR(24)
  x0 += k1; x1 += k2 + 4u;
  TFR(13) TFR(15) TFR(26) TFR(6)
  x0 += k2; x1 += k0 + 5u;
#undef TFR
  return x0 ^ x1;
}

__device__ __forceinline__ float gumbel_from_bits(unsigned bits) {
  float f = __uint_as_float((bits >> 9) | 0x3f800000u) - 1.0f;
  float u = fmaxf(f, TINYF);
  return -logf(-logf(u));
}

// order-preserving float->uint (monotone)
__device__ __forceinline__ unsigned ordf(float v) {
  unsigned b = __float_as_uint(v);
  return (b & 0x80000000u) ? ~b : (b | 0x80000000u);
}

__device__ __forceinline__ unsigned short f2bf(float x) {  // RNE bf16
  unsigned u = __float_as_uint(x);
  return (unsigned short)((u + 0x7FFFu + ((u >> 16) & 1u)) >> 16);
}

// exact f32 rescore (identical FMA order to k_seedvth) + gumbel + rowslot max
__device__ __forceinline__ void exact_push(unsigned grow, unsigned j,
                                           const float* __restrict__ hfin,
                                           const float* __restrict__ items,
                                           unsigned long long* __restrict__ rowslot) {
  const float* hp = hfin + grow * 128;
  const float* ap = items + (size_t)j * 128;
  float acc = 0.f;
  for (int k = 0; k < 128; k += 4) {  // strictly sequential k (matches ref)
    float4 h4 = *(const float4*)(hp + k);
    float4 a4 = *(const float4*)(ap + k);
    acc = fmaf(h4.x, a4.x, acc);
    acc = fmaf(h4.y, a4.y, acc);
    acc = fmaf(h4.z, a4.z, acc);
    acc = fmaf(h4.w, a4.w, acc);
  }
  float v = acc + gumbel_from_bits(tf2x32_xor(0u, grow * 50000u + j));
  unsigned long long pk = ((unsigned long long)ordf(v) << 32) | (0xFFFFFFFFu - j);
  atomicMax(&rowslot[grow], pk);
}

// ---------------- init: zero state + build fractional gumbel cut table ------
// Bcut16[i]: conservative mantissa cut for threshold x_i = i/16. If
// (bits>>9) < Bcut16[i] then g_f32(bits) < x_i, guaranteed (binary search
// against the SAME f32 logf path the rescore uses, -2 safety steps).
__global__ void k_init(unsigned long long* rowslot, float* maxA,
                       unsigned* Bcut16) {
  const int gid = blockIdx.x * 256 + threadIdx.x;
  if (gid < 4096) ((unsigned*)rowslot)[gid] = 0u;
  if (gid == 4096) *maxA = 0.0f;
  if (blockIdx.x == 16) {
    const int k = threadIdx.x;  // 256 thresholds, x = k/16
    const float target = (float)k * 0.0625f;
    unsigned lo = 1u, hi = 1u << 23;  // first B with g(B) >= target
    while (lo < hi) {
      unsigned mid = (lo + hi) >> 1;
      float u = fmaxf((float)mid * 0x1p-23f, TINYF);
      float g = -logf(-logf(u));
      if (g >= target) hi = mid; else lo = mid + 1;
    }
    Bcut16[k] = (lo >= 2u) ? (lo - 2u) : 0u;
  }
}

// ---------------- h = x @ W + b (f64 accumulate) ----------------
__global__ void k_hraw(const float* __restrict__ x, const float* __restrict__ W,
                       const float* __restrict__ b, float* __restrict__ hraw) {
  __shared__ float sx[256];
  const int i = blockIdx.x;
  const int d = threadIdx.x;  // 128 threads
  sx[d] = x[i * 256 + d];
  sx[d + 128] = x[i * 256 + 128 + d];
  __syncthreads();
  double acc = 0.0;
  for (int k = 0; k < 256; ++k)
    acc = fma((double)sx[k], (double)W[k * 128 + d], acc);
  hraw[i * 128 + d] = (float)acc + b[d];
}

// ---------------- BN stats per column (f64) ----------------
__global__ void k_bnstats(const float* __restrict__ hraw,
                          float* __restrict__ meanv, float* __restrict__ rsv) {
  __shared__ double red[256];
  const int d = blockIdx.x;   // 128 blocks
  const int t = threadIdx.x;  // 256 threads
  double s = 0.0;
  for (int i = t; i < 2048; i += 256) s += (double)hraw[i * 128 + d];
  red[t] = s;
  __syncthreads();
  for (int off = 128; off > 0; off >>= 1) {
    if (t < off) red[t] += red[t + off];
    __syncthreads();
  }
  const float m = (float)(red[0] * (1.0 / 2048.0));
  __syncthreads();
  double v = 0.0;
  for (int i = t; i < 2048; i += 256) {
    float dd = __fsub_rn(hraw[i * 128 + d], m);
    v += (double)dd * (double)dd;
  }
  red[t] = v;
  __syncthreads();
  for (int off = 128; off > 0; off >>= 1) {
    if (t < off) red[t] += red[t + off];
    __syncthreads();
  }
  if (t == 0) {
    float var = (float)(red[0] * (1.0 / 2048.0));
    float vpe = __fadd_rn(var, 1e-5f);
    meanv[d] = m;
    rsv[d] = (float)(1.0 / sqrt((double)vpe));
  }
}

// ---------------- apply BN + leaky relu ----------------
__global__ void k_apply(const float* __restrict__ hraw,
                        const float* __restrict__ meanv, const float* __restrict__ rsv,
                        const float* __restrict__ gamma, const float* __restrict__ beta,
                        float* __restrict__ hfin) {
  const int idx = blockIdx.x * 256 + threadIdx.x;
  const int d = idx & 127;
  float h = hraw[idx];
  float hn = __fadd_rn(__fmul_rn(__fmul_rn(__fsub_rn(h, meanv[d]), rsv[d]), gamma[d]), beta[d]);
  hfin[idx] = (hn >= 0.0f) ? hn : __fmul_rn(0.01f, hn);
}

// ---------------- h -> bf16 + row norms ----------------
__global__ void k_hbconv(const float* __restrict__ hfin,
                         unsigned short* __restrict__ hb,
                         float* __restrict__ hnorm) {
  const int r = blockIdx.x;      // 2048
  const int lane = threadIdx.x;  // 64
  float a = hfin[r * 128 + lane];
  float b = hfin[r * 128 + 64 + lane];
  hb[r * 128 + lane] = f2bf(a);
  hb[r * 128 + 64 + lane] = f2bf(b);
  float s = a * a + b * b;
  for (int off = 32; off > 0; off >>= 1) s += __shfl_down(s, off);
  if (lane == 0) hnorm[r] = sqrtf(s) * 1.000001f;
}

// ---------------- items -> bf16 + global max row norm ----------------
__global__ void k_ibconv(const float* __restrict__ items,
                         unsigned short* __restrict__ ib,
                         float* __restrict__ maxA) {
  const int r = blockIdx.x * 4 + (threadIdx.x >> 6);  // 12500 blocks x 4 rows
  const int lane = threadIdx.x & 63;
  float a = items[(size_t)r * 128 + lane];
  float b = items[(size_t)r * 128 + 64 + lane];
  ib[(size_t)r * 128 + lane] = f2bf(a);
  ib[(size_t)r * 128 + 64 + lane] = f2bf(b);
  float s = a * a + b * b;
  for (int off = 32; off > 0; off >>= 1) s += __shfl_down(s, off);
  if (lane == 0) atomicMax((int*)maxA, __float_as_int(sqrtf(s) * 1.000001f));
}

// ---------------- V0 seed over j in [0,1024) + per-row threshold -----------
// vth = V0 - GMAX - eps, eps >= |s_exact - s_bf16| (Cauchy-Schwarz bf16 bound)
__global__ void k_seedvth(const float* __restrict__ hfin,
                          const float* __restrict__ items,
                          const float* __restrict__ hnorm,
                          const float* __restrict__ maxA,
                          float* __restrict__ vth) {
  __shared__ float red[4][256];
  const int t = threadIdx.x;
  const int rbase = blockIdx.x * 4;
  float best[4] = {-INFINITY, -INFINITY, -INFINITY, -INFINITY};
  for (int q = 0; q < 4; ++q) {
    const int j = t + 256 * q;
    float acc[4] = {0.0f, 0.0f, 0.0f, 0.0f};
    const float* ap = items + (size_t)j * 128;
    for (int km = 0; km < 8; ++km) {
#pragma unroll
      for (int e = 0; e < 4; ++e) {
        float4 a4 = *(const float4*)(ap + km * 16 + 4 * e);
        float4 h4[4];
#pragma unroll
        for (int p = 0; p < 4; ++p)
          h4[p] = *(const float4*)(hfin + (rbase + p) * 128 + km * 16 + 4 * e);
#pragma unroll
        for (int p = 0; p < 4; ++p) {
          acc[p] = fmaf(h4[p].x, a4.x, acc[p]);
          acc[p] = fmaf(h4[p].y, a4.y, acc[p]);
          acc[p] = fmaf(h4[p].z, a4.z, acc[p]);
          acc[p] = fmaf(h4[p].w, a4.w, acc[p]);
        }
      }
    }
#pragma unroll
    for (int p = 0; p < 4; ++p) {
      unsigned l = (unsigned)(rbase + p) * 50000u + (unsigned)j;
      float g = gumbel_from_bits(tf2x32_xor(0u, l));
      best[p] = fmaxf(best[p], acc[p] + g);
    }
  }
#pragma unroll
  for (int p = 0; p < 4; ++p) red[p][t] = best[p];
  __syncthreads();
  for (int off = 128; off > 0; off >>= 1) {
    if (t < off) {
#pragma unroll
      for (int p = 0; p < 4; ++p) red[p][t] = fmaxf(red[p][t], red[p][t + off]);
    }
    __syncthreads();
  }
  if (t < 4) {
    const int r = rbase + t;
    vth[r] = red[t][0] - GMAX - (0.0082f * hnorm[r] * maxA[0] + 0.05f);
  }
}

// ---------------- MFMA screening + 2-stage prune + inline exact rescore ----
// grid 12800: c = bid&7 (chunk == XCD, L2-resident), jt = (bid>>3)%25,
// rt = (bid>>3)/25 (32 rows). Stage 1 (s >= vth) -> LDS queue via
// wave-aggregated push. Stage 2 (dense): threefry BITS + 1/16-granular
// mantissa-cut test; survivors (~hundreds/block worst case) get the exact
// f32 rescore inline + packed atomicMax into rowslot (2048 spread addresses).
// NO single-address global atomics anywhere (round 9's 1.6ms was 2M
// atomicAdds on one cand_cnt cacheline).
__global__ __launch_bounds__(256) void k_mfma(
    const unsigned short* __restrict__ hb, const unsigned short* __restrict__ ib,
    const float* __restrict__ vth, const unsigned* __restrict__ Bcut16,
    const float* __restrict__ hfin, const float* __restrict__ items,
    unsigned long long* __restrict__ rowslot) {
  __shared__ unsigned q_key[LQCAP];
  __shared__ float q_val[LQCAP];
  __shared__ unsigned sB[256];
  __shared__ unsigned q_cnt;

  const int t = threadIdx.x;
  const int bid = blockIdx.x;
  const int c = bid & 7;
  const int tmp = bid >> 3;
  const int jt = tmp % 25;
  const int rt = tmp / 25;
  const int r0 = rt * 32;
  const int jlo = c * 6250;
  const int jhi = jlo + 6250;
  const int wid = t >> 6;
  const int lane = t & 63;
  const int m = lane & 15;
  const int q = lane >> 4;
  const int jw = jlo + jt * 256 + wid * 64;

  if (t < 256) sB[t] = Bcut16[t];
  if (t == 0) q_cnt = 0;
  __syncthreads();

  // A fragments: A[m=lane&15][k=q*8+i], 2 M-tiles x 4 K-steps
  short8 afrag[2][4];
  float vthr[2][4];
#pragma unroll
  for (int mt = 0; mt < 2; ++mt) {
    const unsigned short* hrow = hb + (r0 + mt * 16 + m) * 128 + q * 8;
#pragma unroll
    for (int ks = 0; ks < 4; ++ks) afrag[mt][ks] = *(const short8*)(hrow + ks * 32);
#pragma unroll
    for (int reg = 0; reg < 4; ++reg) vthr[mt][reg] = vth[r0 + mt * 16 + q * 4 + reg];
  }

#pragma unroll
  for (int nt = 0; nt < 4; ++nt) {
    const int jn = jw + nt * 16 + m;
    const int jcl = (jn < jhi) ? jn : (jhi - 1);
    const unsigned short* brow = ib + (size_t)jcl * 128 + q * 8;
    f32x4 C0 = {0.f, 0.f, 0.f, 0.f};
    f32x4 C1 = {0.f, 0.f, 0.f, 0.f};
#pragma unroll
    for (int ks = 0; ks < 4; ++ks) {
      short8 bfrag = *(const short8*)(brow + ks * 32);
      C0 = __builtin_amdgcn_mfma_f32_16x16x32_bf16(afrag[0][ks], bfrag, C0, 0, 0, 0);
      C1 = __builtin_amdgcn_mfma_f32_16x16x32_bf16(afrag[1][ks], bfrag, C1, 0, 0, 0);
    }
#pragma unroll
    for (int reg = 0; reg < 4; ++reg) {
#pragma unroll
      for (int mt = 0; mt < 2; ++mt) {
        const float s = (mt == 0) ? C0[reg] : C1[reg];
        const bool pred = (jn < jhi) && (s >= vthr[mt][reg]);
        // wave-aggregated LDS queue push
        unsigned long long mk = __ballot(pred);
        if (mk != 0ull) {
          const int leader = __builtin_ctzll(mk);
          unsigned base = 0u;
          if (lane == leader) base = atomicAdd(&q_cnt, (unsigned)__popcll(mk));
          base = (unsigned)__shfl((int)base, leader, 64);
          if (pred) {
            const unsigned p = (unsigned)(mt * 16 + q * 4 + reg);
            const unsigned my = base + (unsigned)__popcll(mk & ((1ull << lane) - 1ull));
            if (my < LQCAP) {
              q_key[my] = (p << 16) | (unsigned)jn;
              q_val[my] = s;
            } else {  // LDS overflow: exact inline (sound)
              exact_push((unsigned)(r0 + p), (unsigned)jn, hfin, items, rowslot);
            }
          }
        }
      }
    }
  }

  __syncthreads();
  // stage 2: dense, bits-only gumbel bound; survivors -> inline exact rescore
  const unsigned n = (q_cnt < LQCAP) ? q_cnt : LQCAP;
  for (unsigned i = t; i < n; i += 256) {
    const unsigned key = q_key[i];
    const unsigned grow = (unsigned)r0 + (key >> 16);
    const unsigned j = key & 0xFFFFu;
    const float s = q_val[i];
    const float x = vth[grow] + GMAX - s;  // = V0 - eps - s
    const float xk = x * 16.0f - 0.08f;
    if (xk >= 256.0f) continue;            // x > gmax: unreachable
    bool push = true;
    if (xk >= 0.0f) {
      const unsigned bits = tf2x32_xor(0u, grow * 50000u + j);
      push = ((bits >> 9) >= sB[(int)xk]);  // B < cut => g < x => skip (sound)
    }
    if (push) exact_push(grow, j, hfin, items, rowslot);
  }
}

// ---------------- winner + cosine sim (one wave per row) ----------------
__global__ void k_final(const unsigned long long* __restrict__ rowslot,
                        const int* __restrict__ uid, const float* __restrict__ items,
                        float* __restrict__ dout, float* __restrict__ simv) {
  const int r = blockIdx.x;
  const int lane = threadIdx.x;  // 64
  const int bi = (int)(0xFFFFFFFFu - (unsigned)(rowslot[r] & 0xFFFFFFFFull));
  if (lane == 0) dout[r] = (float)bi;

  const int orig = uid[r * 2 + 1];
  float o1 = items[(size_t)orig * 128 + lane];
  float o2 = items[(size_t)orig * 128 + 64 + lane];
  float p1 = items[(size_t)bi * 128 + lane];
  float p2 = items[(size_t)bi * 128 + 64 + lane];
  float d = o1 * p1 + o2 * p2;
  float s1 = o1 * o1 + o2 * o2;
  float s2 = p1 * p1 + p2 * p2;
  for (int off = 32; off > 0; off >>= 1) {
    d += __shfl_down(d, off);
    s1 += __shfl_down(s1, off);
    s2 += __shfl_down(s2, off);
  }
  if (lane == 0) {
    float n1 = fmaxf(sqrtf(s1), 1e-6f);
    float n2 = fmaxf(sqrtf(s2), 1e-6f);
    float sim = d / (n1 * n2);
    simv[r] = (sim + 1.0f) * 0.5f;
  }
}

// ---------------- final scalar reductions ----------------
__global__ void k_reduce(const float* __restrict__ simv, float* __restrict__ dout) {
  __shared__ double rl[256];
  __shared__ double rs[256];
  const int t = threadIdx.x;
  double L = 0.0, S = 0.0;
  for (int i = t; i < 2048; i += 256) {
    double s = (double)simv[i];
    double dd = s - 0.5;
    L += dd * dd;
    S += s;
  }
  rl[t] = L; rs[t] = S;
  __syncthreads();
  for (int off = 128; off > 0; off >>= 1) {
    if (t < off) { rl[t] += rl[t + off]; rs[t] += rs[t + off]; }
    __syncthreads();
  }
  if (t == 0) {
    dout[2048] = (float)(rl[0] * (1.0 / 2048.0));
    dout[2049] = (float)(rs[0] * (1.0 / 2048.0));
  }
}

extern "C" void kernel_launch(void* const* d_in, const int* in_sizes, int n_in,
                              void* d_out, int out_size, void* d_ws, size_t ws_size,
                              hipStream_t stream) {
  const int* uid = (const int*)d_in[0];       // (2048,2) int32
  const float* xfeat = (const float*)d_in[1]; // (2048,256)
  const float* items = (const float*)d_in[2]; // (50000,128)
  const float* W = (const float*)d_in[3];     // (256,128)
  const float* bias = (const float*)d_in[4];  // (128,)
  const float* gamma = (const float*)d_in[5]; // (128,)
  const float* beta = (const float*)d_in[6];  // (128,)

  float* ws = (float*)d_ws;
  float* hraw = ws;                                   // 262144
  float* hfin = ws + 262144;                          // 262144
  float* meanv = ws + 524288;                         // 128
  float* rsv = ws + 524416;                           // 128
  float* hnorm = ws + 524544;                         // 2048
  float* vth = ws + 526592;                           // 2048
  float* simv = ws + 528640;                          // 2048
  float* maxA = ws + 530688;                          // 1 (+1 pad)
  unsigned long long* rowslot =
      (unsigned long long*)(ws + 530690);             // 2048 u64 (8B-aligned)
  unsigned* Bcut16 = (unsigned*)(ws + 534786);        // 256 u32
  unsigned short* hb = (unsigned short*)(ws + 535042);   // 262144 bf16
  unsigned short* ib = (unsigned short*)(ws + 666114);   // 6.4M bf16
  float* dout = (float*)d_out;                        // 2050 floats

  hipLaunchKernelGGL(k_init, dim3(17), dim3(256), 0, stream, rowslot, maxA, Bcut16);
  hipLaunchKernelGGL(k_hraw, dim3(2048), dim3(128), 0, stream, xfeat, W, bias, hraw);
  hipLaunchKernelGGL(k_bnstats, dim3(128), dim3(256), 0, stream, hraw, meanv, rsv);
  hipLaunchKernelGGL(k_apply, dim3(1024), dim3(256), 0, stream, hraw, meanv, rsv, gamma, beta, hfin);
  hipLaunchKernelGGL(k_hbconv, dim3(2048), dim3(64), 0, stream, hfin, hb, hnorm);
  hipLaunchKernelGGL(k_ibconv, dim3(12500), dim3(256), 0, stream, items, ib, maxA);
  hipLaunchKernelGGL(k_seedvth, dim3(512), dim3(256), 0, stream, hfin, items, hnorm, maxA, vth);
  hipLaunchKernelGGL(k_mfma, dim3(12800), dim3(256), 0, stream,
                     hb, ib, vth, Bcut16, hfin, items, rowslot);
  hipLaunchKernelGGL(k_final, dim3(2048), dim3(64), 0, stream, rowslot, uid, items, dout, simv);
  hipLaunchKernelGGL(k_reduce, dim3(1), dim3(256), 0, stream, simv, dout);
}